// Round 21
// baseline (96.704 us; speedup 1.0000x reference)
//
#include <hip/hip_runtime.h>
#include <hip/hip_bf16.h>

// Problem constants
#define Bk 8
#define Nk 10000
#define Ek 160000
#define Hk 128
#define Zk 64
#define CAPk 64      // bucket-CSR capacity; deg ~ Poisson(16), P(deg>=64) ~ 0
#define NBLK 2504    // node blocks (4 nodes each) = 10016 rows

typedef float f32x4 __attribute__((ext_vector_type(4)));
typedef float f32x2 __attribute__((ext_vector_type(2)));
typedef short s16x8 __attribute__((ext_vector_type(8)));
typedef unsigned u32x4 __attribute__((ext_vector_type(4)));

__device__ inline f32x2 pk_fma(f32x2 a, f32x2 b, f32x2 c){
  f32x2 d; asm("v_pk_fma_f32 %0, %1, %2, %3" : "=v"(d) : "v"(a), "v"(b), "v"(c)); return d;
}
__device__ inline f32x2 pk_add(f32x2 a, f32x2 b){
  f32x2 d; asm("v_pk_add_f32 %0, %1, %2" : "=v"(d) : "v"(a), "v"(b)); return d;
}
__device__ inline unsigned pack_bf2(float lo, float hi){
  __hip_bfloat162 p; p.x = __float2bfloat16(lo); p.y = __float2bfloat16(hi);
  return *(unsigned*)&p;
}

// k0: pack WBT (128x256 [W2l|W2r] bf16), zero cur+pooled, fill pax x-slots
// (node-major: pax[n][2b+1] = x[b][n]). grid 313*256 = 80128 threads.
__global__ __launch_bounds__(256) void k0_init(const float* __restrict__ W2l, const float* __restrict__ W2r,
                                               const float* __restrict__ x,
                                               __hip_bfloat16* __restrict__ wbt, int* __restrict__ cur,
                                               float* __restrict__ pooled, float* __restrict__ pax){
  int t = blockIdx.x*256 + threadIdx.x;
  if (t < 128*256){
    int o = t >> 8, k = t & 255;
    float v = (k < 128) ? W2l[o*128+k] : W2r[o*128+(k-128)];
    wbt[t] = __float2bfloat16(v);
  }
  if (t < Nk) cur[t] = 0;
  if (t < Bk*Hk) pooled[t] = 0.f;
  if (t < Nk*Bk){
    int n = t >> 3, b = t & 7;
    pax[n*16 + 2*b + 1] = x[b*Nk + n];
  }
}

// bucket-CSR fill: csrsrc[d*CAP + p] = src, cur[d] = degree
__global__ void k3_fill(const int* __restrict__ ei, int* __restrict__ cur, int* __restrict__ csrsrc){
  int e = blockIdx.x*blockDim.x + threadIdx.x;
  if (e < Ek){
    int s = ei[e], d = ei[Ek+e];
    int p = atomicAdd(&cur[d], 1);
    if (p < CAPk) csrsrc[d*CAPk + p] = s;
  }
}

// agg1 into pax a-slots: one wave per node. Lane (e0=lane>>3, b=lane&7);
// 8 edges in flight, gathering x from pax x-slots (64 B broadcast segments).
__global__ __launch_bounds__(256) void kP2_agg1(const int* __restrict__ cur, const int* __restrict__ csrsrc,
                                                float* __restrict__ pax){
  int wid = threadIdx.x >> 6, lane = threadIdx.x & 63;
  int i = blockIdx.x*4 + wid;
  if (i >= Nk) return;
  int degc = cur[i];
  int deg = min(degc, CAPk);
  const int* colg = csrsrc + i*CAPk;
  int jv = (lane < deg) ? colg[lane] : 0;
  int e0 = lane >> 3, b = lane & 7;
  float s = 0.f;
  for (int base=0; base<deg; base+=8){
    int e = base + e0;
    int j = __shfl(jv, e & 63);
    float v = 0.f;
    if (e < deg) v = pax[j*16 + 2*b + 1];
    s += v;
  }
  s += __shfl_xor(s, 8);
  s += __shfl_xor(s, 16);
  s += __shfl_xor(s, 32);
  if (lane < 8) pax[i*16 + 2*lane] = s / fmaxf((float)degc, 1.f);
}

__device__ inline void mfma_bf16(f32x4& d, s16x8 a, s16x8 b){
  asm("v_mfma_f32_16x16x32_bf16 %0, %1, %2, %0" : "+v"(d) : "v"(a), "v"(b));
}

// Fused layer-2, h1 NEVER materialized: one wave per node; per edge ONE 64 B
// broadcast segment (pax[j], all 8 batches' (a,x)), then in-register recompute
// of h1 contributions: lane = (batch = lane>>3, h-slice = (lane&7)*16), acc
// over edges. Self-h1 same math once. -> A-tile [agg2|h1self] 32 rows (4 nodes
// x 8 batches) -> MFMA vs wbt -> relu+bias -> per-block pooled partial (LDS)
// -> plain store to pblock. No 256B-row gather anywhere.
__global__ __launch_bounds__(256) void kB_fused(const float* __restrict__ pax,
                        const int* __restrict__ cur, const int* __restrict__ csrsrc,
                        const float* __restrict__ W1l, const float* __restrict__ b1,
                        const float* __restrict__ W1r,
                        const __hip_bfloat16* __restrict__ wbt, const float* __restrict__ b2,
                        float* __restrict__ pblock){
  __shared__ char At[32*512];        // 32 rows x 256 bf16, XOR-swizzled
  __shared__ float pblk[1024];       // per-block pooled partial [b][col]
  int tid = threadIdx.x, wid = tid >> 6, lane = tid & 63;
  int tile = blockIdx.x;
  int i = tile*4 + wid;
  int b = lane >> 3;
  int hs = (lane & 7) * 16;

  // per-lane weights for its 16 h's (broadcast across 8 lanes sharing hs)
  f32x2 wl[8], wr[8], bbv[8];
  #pragma unroll
  for (int q=0;q<8;q++){
    float2 t1 = *(const float2*)(W1l + hs + 2*q); wl[q]  = (f32x2){t1.x, t1.y};
    float2 t2 = *(const float2*)(W1r + hs + 2*q); wr[q]  = (f32x2){t2.x, t2.y};
    float2 t3 = *(const float2*)(b1  + hs + 2*q); bbv[q] = (f32x2){t3.x, t3.y};
  }

  int degc = (i < Nk) ? cur[i] : 0;
  int deg = min(degc, CAPk);
  const int* colg = csrsrc + i*CAPk;
  int jv = (lane < deg) ? colg[lane] : 0;

  f32x2 acc[8];
  #pragma unroll
  for (int q=0;q<8;q++) acc[q] = (f32x2){0.f,0.f};

  #pragma unroll 2
  for (int k=0; k<deg; ++k){
    int j = __shfl(jv, k);
    float2 ax = *(const float2*)(pax + j*16 + 2*b);   // 64B segment, broadcast
    f32x2 a2 = (f32x2){ax.x, ax.x};
    f32x2 x2 = (f32x2){ax.y, ax.y};
    #pragma unroll
    for (int q=0;q<8;q++){
      f32x2 t = pk_fma(a2, wl[q], pk_fma(x2, wr[q], bbv[q]));
      t.x = fmaxf(t.x, 0.f); t.y = fmaxf(t.y, 0.f);
      acc[q] = pk_add(acc[q], t);
    }
  }

  unsigned row = (unsigned)(wid*8 + b);
  unsigned swz = (row & 7) << 4;
  char* rowp = At + row*512;
  unsigned hb = (unsigned)((lane & 7) * 32);
  if (i < Nk){
    float inv = 1.f/fmaxf((float)degc, 1.f);
    float2 sax = *(const float2*)(pax + i*16 + 2*b);
    f32x2 a2 = (f32x2){sax.x, sax.x};
    f32x2 x2 = (f32x2){sax.y, sax.y};
    unsigned ag[8], sf[8];
    #pragma unroll
    for (int q=0;q<8;q++){
      ag[q] = pack_bf2(acc[q].x*inv, acc[q].y*inv);
      f32x2 t = pk_fma(a2, wl[q], pk_fma(x2, wr[q], bbv[q]));
      sf[q] = pack_bf2(fmaxf(t.x,0.f), fmaxf(t.y,0.f));
    }
    u32x4 o0 = (u32x4){ag[0],ag[1],ag[2],ag[3]};
    u32x4 o1 = (u32x4){ag[4],ag[5],ag[6],ag[7]};
    u32x4 s0 = (u32x4){sf[0],sf[1],sf[2],sf[3]};
    u32x4 s1 = (u32x4){sf[4],sf[5],sf[6],sf[7]};
    *(u32x4*)(rowp + ((hb      ) ^ swz)) = o0;
    *(u32x4*)(rowp + ((hb + 16 ) ^ swz)) = o1;
    *(u32x4*)(rowp + ((256 + hb) ^ swz)) = s0;
    *(u32x4*)(rowp + ((272 + hb) ^ swz)) = s1;
  } else {
    u32x4 z = (u32x4){0,0,0,0};
    *(u32x4*)(rowp + ((hb      ) ^ swz)) = z;
    *(u32x4*)(rowp + ((hb + 16 ) ^ swz)) = z;
    *(u32x4*)(rowp + ((256 + hb) ^ swz)) = z;
    *(u32x4*)(rowp + ((272 + hb) ^ swz)) = z;
  }
  __syncthreads();

  // phase 2: GEMM 32x256 @ 256x128; wave w -> cols 32w..32w+31
  int lr = lane & 15, lk = lane >> 4;
  f32x4 acc2[2][2];
  #pragma unroll
  for (int mf=0; mf<2; ++mf)
    #pragma unroll
    for (int q=0; q<2; ++q) acc2[mf][q] = (f32x4){0.f,0.f,0.f,0.f};

  unsigned rsw = (unsigned)((lr & 7) << 4);
  #pragma unroll
  for (int kk=0; kk<8; ++kk){
    unsigned cb = kk*64 + lk*16;
    s16x8 a0 = *(const s16x8*)(At + lr*512      + (cb ^ rsw));
    s16x8 a1 = *(const s16x8*)(At + (16+lr)*512 + (cb ^ rsw));
    #pragma unroll
    for (int q=0; q<2; ++q){
      int nf = wid*2 + q;
      s16x8 bfr = *(const s16x8*)(const void*)(wbt + (nf*16+lr)*256 + kk*32 + lk*8);
      mfma_bf16(acc2[0][q], a0, bfr);
      mfma_bf16(acc2[1][q], a1, bfr);
    }
  }

  // epilogue: rows = (node w, batch b): row = w*8+b. Per (q,r): combine the 4
  // same-b rows (mf 0/1 and lk^2 via shfl_xor 32), mask invalid nodes, stash
  // per-block partial in LDS, then one coalesced store to pblock.
  #pragma unroll
  for (int q=0; q<2; ++q){
    int colc = (wid*2+q)*16 + lr;
    float bias = b2[colc];
    #pragma unroll
    for (int r=0;r<4;++r){
      int wnode = (lk*4+r) >> 3;
      float m0 = (tile*4 + wnode     < Nk) ? 1.f : 0.f;
      float m1 = (tile*4 + wnode + 2 < Nk) ? 1.f : 0.f;
      float t = m0*fmaxf(acc2[0][q][r]+bias, 0.f) + m1*fmaxf(acc2[1][q][r]+bias, 0.f);
      t += __shfl_xor(t, 32);
      if (lane < 32) pblk[((lk*4+r)&7)*128 + colc] = t;
    }
  }
  __syncthreads();
  *(f32x4*)(pblock + (size_t)tile*1024 + tid*4) = *(const f32x4*)(pblk + tid*4);
}

// k7a: reduce pblock tiles -> pooled via 313x1024 atomics (measured-free tier)
__global__ __launch_bounds__(256) void k7a_reduce(const float* __restrict__ pblock,
                                                  float* __restrict__ pooled){
  int g = blockIdx.x, t = threadIdx.x;
  float a0=0.f, a1=0.f, a2=0.f, a3=0.f;
  #pragma unroll
  for (int e=0; e<8; ++e){
    int tile = g*8 + e;
    if (tile < NBLK){
      const float* p = pblock + (size_t)tile*1024;
      a0 += p[t]; a1 += p[256+t]; a2 += p[512+t]; a3 += p[768+t];
    }
  }
  atomicAdd(&pooled[t],       a0);
  atomicAdd(&pooled[256 + t], a1);
  atomicAdd(&pooled[512 + t], a2);
  atomicAdd(&pooled[768 + t], a3);
}

__global__ void k7_final(const float* __restrict__ pooled, const float* __restrict__ Wro1,
                         const float* __restrict__ bro1, const float* __restrict__ Wro2,
                         const float* __restrict__ bro2, float* __restrict__ out){
  int b = blockIdx.x, t = threadIdx.x;
  __shared__ float pool[128];
  __shared__ float hid[128];
  pool[t] = pooled[b*Hk + t] * (1.0f/(float)Nk);
  __syncthreads();
  float s = bro1[t];
  for (int d=0; d<128; ++d) s += Wro1[t*128+d]*pool[d];
  hid[t] = fmaxf(s, 0.f);
  __syncthreads();
  if (t < Zk){
    float s2 = bro2[t];
    for (int d=0; d<128; ++d) s2 += Wro2[t*128+d]*hid[d];
    out[b*Zk + t] = s2;
  }
}

extern "C" void kernel_launch(void* const* d_in, const int* in_sizes, int n_in,
                              void* d_out, int out_size, void* d_ws, size_t ws_size,
                              hipStream_t stream) {
  const float* x    = (const float*)d_in[0];
  const int*   ei   = (const int*)d_in[1];
  const float* W1l  = (const float*)d_in[2];
  const float* b1   = (const float*)d_in[3];
  const float* W1r  = (const float*)d_in[4];
  const float* W2l  = (const float*)d_in[5];
  const float* b2   = (const float*)d_in[6];
  const float* W2r  = (const float*)d_in[7];
  const float* Wro1 = (const float*)d_in[8];
  const float* bro1 = (const float*)d_in[9];
  const float* Wro2 = (const float*)d_in[10];
  const float* bro2 = (const float*)d_in[11];
  float* out = (float*)d_out;

  // workspace layout (bytes, 256-aligned)
  char* ws = (char*)d_ws;
  int*   cur    = (int*)(ws + 0);              // 40000
  float* pooled = (float*)(ws + 40448);        // 4096
  __hip_bfloat16* wbt = (__hip_bfloat16*)(ws + 44544);    // 65536
  int*   csrsrc = (int*)(ws + 110080);         // 10016*64*4 = 2564096
  float* pax    = (float*)(ws + 2674176);      // 10016*16*4 = 641024
  float* pblock = (float*)(ws + 3315200);      // 2504*1024*4 = 10256384

  k0_init<<<dim3(313), 256, 0, stream>>>(W2l, W2r, x, wbt, cur, pooled, pax);
  k3_fill<<<dim3((Ek+255)/256), 256, 0, stream>>>(ei, cur, csrsrc);
  kP2_agg1<<<dim3(NBLK), 256, 0, stream>>>(cur, csrsrc, pax);
  kB_fused<<<dim3(NBLK), 256, 0, stream>>>(pax, cur, csrsrc, W1l, b1, W1r, wbt, b2, pblock);
  k7a_reduce<<<dim3(313), 256, 0, stream>>>(pblock, pooled);
  k7_final<<<dim3(Bk), 128, 0, stream>>>(pooled, Wro1, bro1, Wro2, bro2, out);
}